// Round 1
// baseline (6945.654 us; speedup 1.0000x reference)
//
#include <hip/hip_runtime.h>
#include <hip/hip_bf16.h>
#include <math.h>

#define VV 50257
#define SS 1024
#define BB 2
#define DD 768
#define HH 12
#define HDIM 64
#define FF 3072
#define LL 2
#define NT (BB*SS)   // 2048 tokens

// ---------------------------------------------------------------- embedding
__global__ void embed_kernel(const int* __restrict__ idx,
                             const float* __restrict__ tok,
                             const float* __restrict__ pos,
                             float* __restrict__ x) {
    int i = blockIdx.x;            // token index [0, NT)
    int t = idx[i];
    int s = i % SS;
    const float* tr = tok + (size_t)t * DD;
    const float* pr = pos + (size_t)s * DD;
    float* xr = x + (size_t)i * DD;
    for (int d = threadIdx.x; d < DD; d += blockDim.x)
        xr[d] = tr[d] + pr[d];
}

// ---------------------------------------------------------------- layernorm
__inline__ __device__ float wave_reduce_sum(float v) {
    #pragma unroll
    for (int o = 32; o > 0; o >>= 1) v += __shfl_down(v, o);
    return v;
}

__global__ void ln_kernel(const float* __restrict__ x,
                          const float* __restrict__ w,
                          const float* __restrict__ b,
                          float* __restrict__ out) {
    int i = blockIdx.x;
    const float* xr = x + (size_t)i * DD;
    float s = 0.f, ss = 0.f;
    for (int d = threadIdx.x; d < DD; d += blockDim.x) {
        float v = xr[d];
        s += v; ss += v * v;
    }
    __shared__ float sred[8];
    __shared__ float smean, srstd;
    int wid = threadIdx.x >> 6, lane = threadIdx.x & 63;
    float rs = wave_reduce_sum(s);
    float rss = wave_reduce_sum(ss);
    if (lane == 0) { sred[wid] = rs; sred[4 + wid] = rss; }
    __syncthreads();
    if (threadIdx.x == 0) {
        float ts = 0.f, tss = 0.f;
        #pragma unroll
        for (int k = 0; k < 4; k++) { ts += sred[k]; tss += sred[4 + k]; }
        float m = ts / DD;
        float var = tss / DD - m * m;
        smean = m;
        srstd = rsqrtf(var + 1e-5f);
    }
    __syncthreads();
    float m = smean, r = srstd;
    float* orow = out + (size_t)i * DD;
    for (int d = threadIdx.x; d < DD; d += blockDim.x)
        orow[d] = (xr[d] - m) * r * w[d] + b[d];
}

// ---------------------------------------------------------------- GELU
__device__ __forceinline__ float gelu_f(float z) {
    const float c = 0.7978845608028654f; // sqrt(2/pi)
    float t = tanhf(c * (z + 0.044715f * z * z * z));
    return 0.5f * z * (1.0f + t);
}

// ---------------------------------------------------------------- GEMM NN
// C[M,Nn] = A[M,K] @ W[K,Nn] + bias (+ gelu) (+ residual)
// Tile 64x64, BK=16, 256 threads, 4x4 per thread. M,Nn,K multiples of 64/16.
template<int ACT, bool RES>
__global__ void gemm_nn(const float* __restrict__ A,
                        const float* __restrict__ W,
                        const float* __restrict__ bias,
                        const float* __restrict__ resid,
                        float* __restrict__ C,
                        int M, int Nn, int K) {
    __shared__ float As[16][65];
    __shared__ float Ws[16][65];
    const int bm = blockIdx.y * 64;
    const int bn = blockIdx.x * 64;
    const int tid = threadIdx.x;
    const int tx = tid & 15, ty = tid >> 4;
    float acc[4][4] = {};
    for (int k0 = 0; k0 < K; k0 += 16) {
        #pragma unroll
        for (int r = 0; r < 4; r++) {
            int e = tid + 256 * r;
            int m = e >> 4, kk = e & 15;
            As[kk][m] = A[(size_t)(bm + m) * K + k0 + kk];
        }
        #pragma unroll
        for (int r = 0; r < 4; r++) {
            int e = tid + 256 * r;
            int kk = e >> 6, n = e & 63;
            Ws[kk][n] = W[(size_t)(k0 + kk) * Nn + bn + n];
        }
        __syncthreads();
        #pragma unroll
        for (int kk = 0; kk < 16; kk++) {
            float a[4], wv4[4];
            #pragma unroll
            for (int ii = 0; ii < 4; ii++) a[ii] = As[kk][ty * 4 + ii];
            #pragma unroll
            for (int jj = 0; jj < 4; jj++) wv4[jj] = Ws[kk][tx * 4 + jj];
            #pragma unroll
            for (int ii = 0; ii < 4; ii++)
                #pragma unroll
                for (int jj = 0; jj < 4; jj++)
                    acc[ii][jj] += a[ii] * wv4[jj];
        }
        __syncthreads();
    }
    #pragma unroll
    for (int ii = 0; ii < 4; ii++) {
        int row = bm + ty * 4 + ii;
        #pragma unroll
        for (int jj = 0; jj < 4; jj++) {
            int col = bn + tx * 4 + jj;
            float v = acc[ii][jj] + bias[col];
            if (ACT == 1) v = gelu_f(v);
            if (RES) v += resid[(size_t)row * Nn + col];
            C[(size_t)row * Nn + col] = v;
        }
    }
}

// ---------------------------------------------------------------- GEMM NT (LM head)
// C[M,Nn] = A[M,K] @ Bm[Nn,K]^T ; Nn (=V) not a multiple of 64 -> guarded.
__global__ void gemm_nt(const float* __restrict__ A,
                        const float* __restrict__ Bm,
                        float* __restrict__ C,
                        int M, int Nn, int K) {
    __shared__ float As[16][65];
    __shared__ float Bs[16][65];
    const int bm = blockIdx.y * 64;
    const int bn = blockIdx.x * 64;
    const int tid = threadIdx.x;
    const int tx = tid & 15, ty = tid >> 4;
    float acc[4][4] = {};
    for (int k0 = 0; k0 < K; k0 += 16) {
        #pragma unroll
        for (int r = 0; r < 4; r++) {
            int e = tid + 256 * r;
            int m = e >> 4, kk = e & 15;
            As[kk][m] = A[(size_t)(bm + m) * K + k0 + kk];
        }
        #pragma unroll
        for (int r = 0; r < 4; r++) {
            int e = tid + 256 * r;
            int n = e >> 4, kk = e & 15;
            int gn = bn + n;
            Bs[kk][n] = (gn < Nn) ? Bm[(size_t)gn * K + k0 + kk] : 0.f;
        }
        __syncthreads();
        #pragma unroll
        for (int kk = 0; kk < 16; kk++) {
            float a[4], bv4[4];
            #pragma unroll
            for (int ii = 0; ii < 4; ii++) a[ii] = As[kk][ty * 4 + ii];
            #pragma unroll
            for (int jj = 0; jj < 4; jj++) bv4[jj] = Bs[kk][tx * 4 + jj];
            #pragma unroll
            for (int ii = 0; ii < 4; ii++)
                #pragma unroll
                for (int jj = 0; jj < 4; jj++)
                    acc[ii][jj] += a[ii] * bv4[jj];
        }
        __syncthreads();
    }
    #pragma unroll
    for (int ii = 0; ii < 4; ii++) {
        int row = bm + ty * 4 + ii;
        #pragma unroll
        for (int jj = 0; jj < 4; jj++) {
            int col = bn + tx * 4 + jj;
            if (col < Nn) C[(size_t)row * Nn + col] = acc[ii][jj];
        }
    }
}

// ---------------------------------------------------------------- attention
// One wave (64 threads) per (q-position, b*h). Scores in LDS, masked softmax,
// then PV accumulate with lane = head-dim.
__global__ void attn_kernel(const float* __restrict__ q,
                            const float* __restrict__ k,
                            const float* __restrict__ v,
                            float* __restrict__ out) {
    const int sq = blockIdx.x;
    const int bh = blockIdx.y;
    const int b = bh / HH, h = bh % HH;
    const int lane = threadIdx.x;
    __shared__ float qs[HDIM];
    __shared__ float sc[SS];
    const size_t base = (size_t)b * SS * DD + (size_t)h * HDIM;
    qs[lane] = q[base + (size_t)sq * DD + lane];
    __syncthreads();
    const float scale = 0.125f; // 1/sqrt(64)
    const int nk = sq + 1;
    for (int j0 = 0; j0 < nk; j0 += 64) {
        int j = j0 + lane;
        if (j < nk) {
            const float* kr = k + base + (size_t)j * DD;
            float acc = 0.f;
            #pragma unroll
            for (int d = 0; d < HDIM; d++) acc += qs[d] * kr[d];
            sc[j] = acc * scale;
        }
    }
    __syncthreads();
    float m = -1e30f;
    for (int j = lane; j < nk; j += 64) m = fmaxf(m, sc[j]);
    #pragma unroll
    for (int o = 32; o > 0; o >>= 1) m = fmaxf(m, __shfl_down(m, o));
    m = __shfl(m, 0);
    float ssum = 0.f;
    for (int j = lane; j < nk; j += 64) {
        float e = __expf(sc[j] - m);
        sc[j] = e;
        ssum += e;
    }
    #pragma unroll
    for (int o = 32; o > 0; o >>= 1) ssum += __shfl_down(ssum, o);
    ssum = __shfl(ssum, 0);
    const float inv = 1.0f / ssum;
    __syncthreads();
    float oacc = 0.f;
    for (int j = 0; j < nk; j++)
        oacc += sc[j] * v[base + (size_t)j * DD + lane];
    out[base + (size_t)sq * DD + lane] = oacc * inv;
}

// ---------------------------------------------------------------- launch
extern "C" void kernel_launch(void* const* d_in, const int* in_sizes, int n_in,
                              void* d_out, int out_size, void* d_ws, size_t ws_size,
                              hipStream_t stream) {
    const int*   word_idx = (const int*)  d_in[0];
    const float* tok_emb  = (const float*)d_in[1];
    const float* pos_emb  = (const float*)d_in[2];
    const float* ln1_w    = (const float*)d_in[3];
    const float* ln1_b    = (const float*)d_in[4];
    const float* wq       = (const float*)d_in[5];
    const float* bq       = (const float*)d_in[6];
    const float* wk       = (const float*)d_in[7];
    const float* bk       = (const float*)d_in[8];
    const float* wv       = (const float*)d_in[9];
    const float* bv       = (const float*)d_in[10];
    const float* wo       = (const float*)d_in[11];
    const float* bo       = (const float*)d_in[12];
    const float* ln2_w    = (const float*)d_in[13];
    const float* ln2_b    = (const float*)d_in[14];
    const float* w1       = (const float*)d_in[15];
    const float* b1       = (const float*)d_in[16];
    const float* w2       = (const float*)d_in[17];
    const float* b2       = (const float*)d_in[18];
    const float* lnf_w    = (const float*)d_in[19];
    const float* lnf_b    = (const float*)d_in[20];
    float* out = (float*)d_out;

    float* x   = (float*)d_ws;
    float* hbf = x   + (size_t)NT * DD;
    float* qb  = hbf + (size_t)NT * DD;
    float* kb  = qb  + (size_t)NT * DD;
    float* vb  = kb  + (size_t)NT * DD;
    float* att = vb  + (size_t)NT * DD;
    float* mid = att + (size_t)NT * DD;   // NT x FF

    embed_kernel<<<NT, 256, 0, stream>>>(word_idx, tok_emb, pos_emb, x);

    dim3 g_dd(DD / 64, NT / 64);     // 12 x 32
    dim3 g_df(FF / 64, NT / 64);     // 48 x 32

    for (int l = 0; l < LL; l++) {
        const float* wq_l = wq + (size_t)l * DD * DD;
        const float* wk_l = wk + (size_t)l * DD * DD;
        const float* wv_l = wv + (size_t)l * DD * DD;
        const float* wo_l = wo + (size_t)l * DD * DD;
        const float* w1_l = w1 + (size_t)l * DD * FF;
        const float* w2_l = w2 + (size_t)l * FF * DD;

        ln_kernel<<<NT, 256, 0, stream>>>(x, ln1_w + l * DD, ln1_b + l * DD, hbf);
        gemm_nn<0, false><<<g_dd, 256, 0, stream>>>(hbf, wq_l, bq + l * DD, nullptr, qb, NT, DD, DD);
        gemm_nn<0, false><<<g_dd, 256, 0, stream>>>(hbf, wk_l, bk + l * DD, nullptr, kb, NT, DD, DD);
        gemm_nn<0, false><<<g_dd, 256, 0, stream>>>(hbf, wv_l, bv + l * DD, nullptr, vb, NT, DD, DD);
        attn_kernel<<<dim3(SS, BB * HH), 64, 0, stream>>>(qb, kb, vb, att);
        gemm_nn<0, true><<<g_dd, 256, 0, stream>>>(att, wo_l, bo + l * DD, x, x, NT, DD, DD);
        ln_kernel<<<NT, 256, 0, stream>>>(x, ln2_w + l * DD, ln2_b + l * DD, hbf);
        gemm_nn<1, false><<<g_df, 256, 0, stream>>>(hbf, w1_l, b1 + l * FF, nullptr, mid, NT, FF, DD);
        gemm_nn<0, true><<<g_dd, 256, 0, stream>>>(mid, w2_l, b2 + l * DD, x, x, NT, DD, FF);
    }

    ln_kernel<<<NT, 256, 0, stream>>>(x, lnf_w, lnf_b, hbf);
    gemm_nt<<<dim3((VV + 63) / 64, NT / 64), 256, 0, stream>>>(hbf, tok_emb, out, NT, VV, DD);
}